// Round 1
// baseline (3739.155 us; speedup 1.0000x reference)
//
#include <hip/hip_runtime.h>
#include <hip/hip_bf16.h>
#include <math.h>

#define NN 1536
#define FF 32
#define HH 64
#define EE (NN*(NN-1)/2)   // 1178880 = 4605*256 exactly
#define BN_EPS 1e-5f
#define SLOPE 0.01f

__device__ __forceinline__ float lrelu_f(float v){ return v >= 0.f ? v : SLOPE*v; }

// ---------------------------------------------------------------------------
// exclusive prefix-sum over nodes (the segment_sum on triu edges) fused with
// u = (1+eps)*x + agg.  One block, (64 cols x 16 row-chunks).
// input stride ld, output stride fixed 64.
__global__ void k_scan(const float* __restrict__ x, int ld,
                       float* __restrict__ u,
                       const float* __restrict__ eps_p, int D) {
  __shared__ float part[16][64];
  int c = threadIdx.x, t = threadIdx.y;
  const int chunk = NN / 16;  // 96
  float s = 0.f;
  if (c < D) {
    for (int n = t*chunk; n < (t+1)*chunk; ++n) s += x[n*ld + c];
  }
  part[t][c] = s;
  __syncthreads();
  if (c >= D) return;
  float run = 0.f;
  for (int i = 0; i < t; ++i) run += part[i][c];
  float e1 = 1.f + eps_p[0];
  for (int n = t*chunk; n < (t+1)*chunk; ++n) {
    float v = x[n*ld + c];
    u[n*64 + c] = e1*v + run;   // exclusive: add before including row n
    run += v;
  }
}

// ---------------------------------------------------------------------------
// out[n][j] = act( sum_k in[n][k]*W[k][j] + bias[j] ) (+ res[n][j])
// W row-major [Din, Dout].  block = 4 rows x 64 cols, grid = NN/4.
// act: 0 none, 1 relu, 2 lrelu
__global__ __launch_bounds__(256) void k_mm(
    const float* __restrict__ in, int ld_in, int Din,
    const float* __restrict__ W, const float* __restrict__ bias,
    float* __restrict__ out, int ld_out, int Dout,
    int act, const float* __restrict__ res, int ld_res) {
  __shared__ float Ws[64*64];
  int tid = threadIdx.x;
  int tot = Din * Dout;
  for (int i = tid; i < tot; i += 256) Ws[i] = W[i];
  __syncthreads();
  int n = blockIdx.x*4 + (tid >> 6);
  int j = tid & 63;
  if (j >= Dout) return;
  float acc = bias ? bias[j] : 0.f;
  const float* row = in + n*ld_in;
  for (int k = 0; k < Din; ++k) acc = fmaf(row[k], Ws[k*Dout + j], acc);
  if (act == 1) acc = fmaxf(acc, 0.f);
  else if (act == 2) acc = lrelu_f(acc);
  if (res) acc += res[n*ld_res + j];
  out[n*ld_out + j] = acc;
}

// ---------------------------------------------------------------------------
// batch-norm statistics over rows: stats[c]=mean, stats[64+c]=biased var
__global__ void k_bnstats(const float* __restrict__ z, float* __restrict__ stats) {
  __shared__ float ps[16][64];
  __shared__ float pq[16][64];
  int c = threadIdx.x, t = threadIdx.y;
  const int chunk = NN / 16;
  float s = 0.f, q = 0.f;
  for (int n = t*chunk; n < (t+1)*chunk; ++n) {
    float v = z[n*64 + c];
    s += v; q += v*v;
  }
  ps[t][c] = s; pq[t][c] = q;
  __syncthreads();
  if (t == 0) {
    float S = 0.f, Q = 0.f;
    for (int i = 0; i < 16; ++i) { S += ps[i][c]; Q += pq[i][c]; }
    float mean = S / NN;
    float var  = Q / NN - mean*mean;
    stats[c] = mean;
    stats[64 + c] = var;
  }
}

// h = lrelu( (z-mean)*rsqrt(var+eps)*g + be )
__global__ __launch_bounds__(256) void k_bnapply(
    const float* __restrict__ z, const float* __restrict__ stats,
    const float* __restrict__ g, const float* __restrict__ be,
    float* __restrict__ out) {
  int i = blockIdx.x*256 + threadIdx.x;   // i < NN*64
  int c = i & 63;
  float mean = stats[c], var = stats[64 + c];
  float v = (z[i] - mean) * rsqrtf(var + BN_EPS) * g[c] + be[c];
  out[i] = lrelu_f(v);
}

// ---------------------------------------------------------------------------
__device__ __forceinline__ int ebase(int s) { return s*(2*NN - 1 - s)/2; }

// edge predictor: per edge e=(s,t), l1=relu(A[s]+B[t]) (b1 folded into A),
// l2=relu(l1@W2+b2), l3=relu(l2@W3+b3), p=sigmoid(l3.w4+b4)
__global__ __launch_bounds__(256, 2) void k_edges(
    const float* __restrict__ A, const float* __restrict__ Bm,
    const float* __restrict__ W2, const float* __restrict__ b2,
    const float* __restrict__ W3, const float* __restrict__ b3,
    const float* __restrict__ w4, const float* __restrict__ b4,
    float* __restrict__ out) {
  __shared__ float W2s[64*64];
  __shared__ float W3s[64*64];
  __shared__ float b2s[64], b3s[64], w4s[64];
  __shared__ float b4s;
  int tid = threadIdx.x;
  for (int i = tid; i < 4096; i += 256) { W2s[i] = W2[i]; W3s[i] = W3[i]; }
  if (tid < 64) { b2s[tid] = b2[tid]; b3s[tid] = b3[tid]; w4s[tid] = w4[tid]; }
  if (tid == 0) b4s = b4[0];
  __syncthreads();

  int idx = blockIdx.x*256 + tid;
  if (idx >= EE) return;

  // decode (s,t), s<t, from row-major triu linear index
  float disc = (float)((2*NN-1)*(2*NN-1) - 8*idx);
  int s = (int)((2.f*NN - 1.f - sqrtf(disc)) * 0.5f);
  if (s < 0) s = 0;
  if (s > NN-2) s = NN-2;
  while (s > 0 && idx < ebase(s)) --s;
  while (idx >= ebase(s+1)) ++s;
  int t = s + 1 + (idx - ebase(s));

  float l1[64], l2[64];
  const float4* Ap = (const float4*)(A + s*64);
  const float4* Bp = (const float4*)(Bm + t*64);
#pragma unroll
  for (int i = 0; i < 16; ++i) {
    float4 a = Ap[i];
    float4 b = Bp[i];
    l1[4*i+0] = fmaxf(a.x + b.x, 0.f);
    l1[4*i+1] = fmaxf(a.y + b.y, 0.f);
    l1[4*i+2] = fmaxf(a.z + b.z, 0.f);
    l1[4*i+3] = fmaxf(a.w + b.w, 0.f);
  }

  // layer 2: l2 = relu(l1 @ W2 + b2)
#pragma unroll
  for (int j = 0; j < 16; ++j) {
    float4 bb = *(const float4*)&b2s[4*j];
    l2[4*j+0] = bb.x; l2[4*j+1] = bb.y; l2[4*j+2] = bb.z; l2[4*j+3] = bb.w;
  }
#pragma unroll
  for (int k = 0; k < 64; ++k) {
    float a = l1[k];
#pragma unroll
    for (int jj = 0; jj < 16; ++jj) {
      float4 w = *(const float4*)&W2s[k*64 + 4*jj];
      l2[4*jj+0] = fmaf(a, w.x, l2[4*jj+0]);
      l2[4*jj+1] = fmaf(a, w.y, l2[4*jj+1]);
      l2[4*jj+2] = fmaf(a, w.z, l2[4*jj+2]);
      l2[4*jj+3] = fmaf(a, w.w, l2[4*jj+3]);
    }
  }
#pragma unroll
  for (int j = 0; j < 64; ++j) l2[j] = fmaxf(l2[j], 0.f);

  // layer 3: l1 = relu(l2 @ W3 + b3)
#pragma unroll
  for (int j = 0; j < 16; ++j) {
    float4 bb = *(const float4*)&b3s[4*j];
    l1[4*j+0] = bb.x; l1[4*j+1] = bb.y; l1[4*j+2] = bb.z; l1[4*j+3] = bb.w;
  }
#pragma unroll
  for (int k = 0; k < 64; ++k) {
    float a = l2[k];
#pragma unroll
    for (int jj = 0; jj < 16; ++jj) {
      float4 w = *(const float4*)&W3s[k*64 + 4*jj];
      l1[4*jj+0] = fmaf(a, w.x, l1[4*jj+0]);
      l1[4*jj+1] = fmaf(a, w.y, l1[4*jj+1]);
      l1[4*jj+2] = fmaf(a, w.z, l1[4*jj+2]);
      l1[4*jj+3] = fmaf(a, w.w, l1[4*jj+3]);
    }
  }

  // layer 4: logit = relu(l1) . w4 + b4
  float acc = b4s;
#pragma unroll
  for (int k = 0; k < 64; ++k) acc = fmaf(fmaxf(l1[k], 0.f), w4s[k], acc);

  float p = 1.f / (1.f + expf(-acc));
  out[s*NN + t] = p;
  out[t*NN + s] = p;
}

__global__ void k_diag(float* __restrict__ out) {
  int i = blockIdx.x*256 + threadIdx.x;
  if (i < NN) out[i*NN + i] = 0.f;
}

// ---------------------------------------------------------------------------
extern "C" void kernel_launch(void* const* d_in, const int* in_sizes, int n_in,
                              void* d_out, int out_size, void* d_ws, size_t ws_size,
                              hipStream_t stream) {
  const float* nf     = (const float*)d_in[1];
  const float* c1_eps = (const float*)d_in[2];
  const float* c1_w1  = (const float*)d_in[3];
  const float* c1_b1  = (const float*)d_in[4];
  const float* c1_w2  = (const float*)d_in[5];
  const float* c1_b2  = (const float*)d_in[6];
  const float* c1_g   = (const float*)d_in[7];
  const float* c1_be  = (const float*)d_in[8];
  const float* cv_eps = (const float*)d_in[9];
  const float* cv_w1  = (const float*)d_in[10];
  const float* cv_b1  = (const float*)d_in[11];
  const float* cv_w2  = (const float*)d_in[12];
  const float* cv_b2  = (const float*)d_in[13];
  const float* cv_g   = (const float*)d_in[14];
  const float* cv_be  = (const float*)d_in[15];
  const float* lin1_w = (const float*)d_in[16];
  const float* lin1_b = (const float*)d_in[17];
  const float* lin2_w = (const float*)d_in[18];
  const float* lin2_b = (const float*)d_in[19];
  const float* ep_w1  = (const float*)d_in[20];
  const float* ep_b1  = (const float*)d_in[21];
  const float* ep_w2  = (const float*)d_in[22];
  const float* ep_b2  = (const float*)d_in[23];
  const float* ep_w3  = (const float*)d_in[24];
  const float* ep_b3  = (const float*)d_in[25];
  const float* ep_w4  = (const float*)d_in[26];
  const float* ep_b4  = (const float*)d_in[27];

  float* ws = (float*)d_ws;
  float* u     = ws;                 // [NN,64]
  float* z1    = u  + NN*64;         // [NN,64]
  float* z2    = z1 + NN*64;         // [NN,64]
  float* h     = z2 + NN*64;         // [NN,64]
  float* stats = h  + NN*64;         // [128]
  float* Abuf  = stats + 128;        // [NN,64]
  float* Bbuf  = Abuf + NN*64;       // [NN,64]
  float* hf    = Bbuf + NN*64;       // [NN,32]

  dim3 b2d(64, 16);
  float* out = (float*)d_out;

  // ---- GIN layer 1 (F=32 -> H=64) ----
  k_scan<<<1, b2d, 0, stream>>>(nf, FF, u, c1_eps, FF);
  k_mm<<<NN/4, 256, 0, stream>>>(u, 64, FF, c1_w1, c1_b1, z1, 64, HH, 1, nullptr, 0);
  k_mm<<<NN/4, 256, 0, stream>>>(z1, 64, HH, c1_w2, c1_b2, z2, 64, HH, 1, nullptr, 0);
  k_bnstats<<<1, b2d, 0, stream>>>(z2, stats);
  k_bnapply<<<NN*64/256, 256, 0, stream>>>(z2, stats, c1_g, c1_be, h);

  // ---- GIN layers 2..3 (H -> H) ----
  for (int i = 0; i < 2; ++i) {
    k_scan<<<1, b2d, 0, stream>>>(h, 64, u, cv_eps + i, HH);
    k_mm<<<NN/4, 256, 0, stream>>>(u, 64, HH, cv_w1 + i*HH*HH, cv_b1 + i*HH, z1, 64, HH, 1, nullptr, 0);
    k_mm<<<NN/4, 256, 0, stream>>>(z1, 64, HH, cv_w2 + i*HH*HH, cv_b2 + i*HH, z2, 64, HH, 1, nullptr, 0);
    k_bnstats<<<1, b2d, 0, stream>>>(z2, stats);
    k_bnapply<<<NN*64/256, 256, 0, stream>>>(z2, stats, cv_g + i*HH, cv_be + i*HH, h);
  }

  // ---- projection head ----
  k_mm<<<NN/4, 256, 0, stream>>>(h, 64, HH, lin1_w, lin1_b, z1, 64, HH, 2, nullptr, 0);
  k_mm<<<NN/4, 256, 0, stream>>>(z1, 64, HH, lin2_w, lin2_b, hf, FF, FF, 2, nf, FF);

  // ---- edge-layer-1 factorization: A = hf@W1a + b1, B = hf@W1b ----
  k_mm<<<NN/4, 256, 0, stream>>>(hf, FF, FF, ep_w1,            ep_b1,   Abuf, 64, HH, 0, nullptr, 0);
  k_mm<<<NN/4, 256, 0, stream>>>(hf, FF, FF, ep_w1 + FF*HH,    nullptr, Bbuf, 64, HH, 0, nullptr, 0);

  // ---- edge MLP over all triu edges ----
  k_edges<<<(EE + 255)/256, 256, 0, stream>>>(Abuf, Bbuf, ep_w2, ep_b2, ep_w3, ep_b3,
                                              ep_w4, ep_b4, out);
  k_diag<<<(NN + 255)/256, 256, 0, stream>>>(out);
}

// Round 2
// 183.584 us; speedup vs baseline: 20.3676x; 20.3676x over previous
//
#include <hip/hip_runtime.h>
#include <hip/hip_bf16.h>
#include <math.h>

#define NN 1536
#define FF 32
#define HH 64
#define EE (NN*(NN-1)/2)   // 1178880 = 73680 * 16
#define NGRP (EE/16)       // 73680
#define GPW 18             // groups per wave; 1024 blocks * 4 waves * 18 = 73728
#define BN_EPS 1e-5f
#define SLOPE 0.01f

typedef __bf16 v8bf __attribute__((ext_vector_type(8)));
typedef float  f32x4 __attribute__((ext_vector_type(4)));

__device__ __forceinline__ float lrelu_f(float v){ return v >= 0.f ? v : SLOPE*v; }

__device__ __forceinline__ unsigned short f2bf(float f) {
  union { float f; unsigned u; } v; v.f = f;
  unsigned u = v.u + 0x7fffu + ((v.u >> 16) & 1u);   // RNE
  return (unsigned short)(u >> 16);
}

// ---------------------------------------------------------------------------
// layer-1 scan: u = (1+eps)*x + exclusive_prefix_sum(x). One block, 64x16.
__global__ void k_scan(const float* __restrict__ x, int ld,
                       float* __restrict__ u,
                       const float* __restrict__ eps_p, int D) {
  __shared__ float part[16][64];
  int c = threadIdx.x, w = threadIdx.y;
  const int chunk = NN / 16;  // 96
  float s = 0.f;
  if (c < D) for (int n = w*chunk; n < (w+1)*chunk; ++n) s += x[n*ld + c];
  part[w][c] = s;
  __syncthreads();
  if (c >= D) return;
  float run = 0.f;
  for (int i = 0; i < w; ++i) run += part[i][c];
  float e1 = 1.f + eps_p[0];
  for (int n = w*chunk; n < (w+1)*chunk; ++n) {
    float v = x[n*ld + c];
    u[n*64 + c] = e1*v + run;
    run += v;
  }
}

// BN-apply + lrelu + scan fused (layers 2..3 front-end)
__global__ void k_scanbn(const float* __restrict__ z, const float* __restrict__ stats,
                         const float* __restrict__ gg, const float* __restrict__ be,
                         const float* __restrict__ eps_p, float* __restrict__ u) {
  __shared__ float part[16][64];
  int c = threadIdx.x, w = threadIdx.y;
  float mean = stats[c], inv = rsqrtf(stats[64 + c] + BN_EPS);
  float ga = gg[c], bb = be[c];
  const int chunk = NN / 16;
  float s = 0.f;
  for (int n = w*chunk; n < (w+1)*chunk; ++n)
    s += lrelu_f((z[n*64 + c] - mean)*inv*ga + bb);
  part[w][c] = s;
  __syncthreads();
  float run = 0.f;
  for (int i = 0; i < w; ++i) run += part[i][c];
  float e1 = 1.f + eps_p[0];
  for (int n = w*chunk; n < (w+1)*chunk; ++n) {
    float hv = lrelu_f((z[n*64 + c] - mean)*inv*ga + bb);
    u[n*64 + c] = e1*hv + run;
    run += hv;
  }
}

// fused double matmul: z = relu(relu(u@W1+b1)@W2+b2). 4 rows/block.
__global__ __launch_bounds__(256) void k_mm2(
    const float* __restrict__ in, int Din,
    const float* __restrict__ W1, const float* __restrict__ b1,
    const float* __restrict__ W2, const float* __restrict__ b2,
    float* __restrict__ outz) {
  __shared__ float W1s[64*64];
  __shared__ float W2s[64*64];
  __shared__ float t1s[4][64];
  int tid = threadIdx.x;
  for (int i = tid; i < Din*64; i += 256) W1s[i] = W1[i];
  for (int i = tid; i < 4096; i += 256)   W2s[i] = W2[i];
  __syncthreads();
  int rloc = tid >> 6, j = tid & 63;
  int row = blockIdx.x*4 + rloc;
  const float* r = in + row*64;
  float a = b1[j];
  for (int k = 0; k < Din; ++k) a = fmaf(r[k], W1s[k*64 + j], a);
  t1s[rloc][j] = fmaxf(a, 0.f);
  __syncthreads();
  float z = b2[j];
  const float* tr = t1s[rloc];
  for (int k = 0; k < 64; ++k) z = fmaf(tr[k], W2s[k*64 + j], z);
  outz[row*64 + j] = fmaxf(z, 0.f);
}

// batch-norm statistics
__global__ void k_bnstats(const float* __restrict__ z, float* __restrict__ stats) {
  __shared__ float ps[16][64];
  __shared__ float pq[16][64];
  int c = threadIdx.x, w = threadIdx.y;
  const int chunk = NN / 16;
  float s = 0.f, q = 0.f;
  for (int n = w*chunk; n < (w+1)*chunk; ++n) {
    float v = z[n*64 + c];
    s += v; q += v*v;
  }
  ps[w][c] = s; pq[w][c] = q;
  __syncthreads();
  if (w == 0) {
    float S = 0.f, Q = 0.f;
    for (int i = 0; i < 16; ++i) { S += ps[i][c]; Q += pq[i][c]; }
    float mean = S / NN;
    stats[c] = mean;
    stats[64 + c] = Q / NN - mean*mean;
  }
}

// head: h3=lrelu(BN(z)); hf=lrelu(lrelu(h3@lin1)@lin2)+nf; A=hf@W1a+b1e; B=hf@W1b
__global__ __launch_bounds__(256) void k_head(
    const float* __restrict__ z, const float* __restrict__ stats,
    const float* __restrict__ gg, const float* __restrict__ be,
    const float* __restrict__ l1w, const float* __restrict__ l1b,
    const float* __restrict__ l2w, const float* __restrict__ l2b,
    const float* __restrict__ nf,
    const float* __restrict__ epw1, const float* __restrict__ epb1,
    float* __restrict__ A, float* __restrict__ Bm) {
  __shared__ float W1s[64*64];
  __shared__ float W2s[64*32];
  __shared__ float Was[32*64];
  __shared__ float Wbs[32*64];
  __shared__ float t0[4][64], t1[4][64], t2[4][32];
  int tid = threadIdx.x;
  for (int i = tid; i < 4096; i += 256) W1s[i] = l1w[i];
  for (int i = tid; i < 2048; i += 256) { W2s[i] = l2w[i]; Was[i] = epw1[i]; Wbs[i] = epw1[2048 + i]; }
  __syncthreads();
  int rloc = tid >> 6, j = tid & 63;
  int row = blockIdx.x*4 + rloc;
  float mean = stats[j], inv = rsqrtf(stats[64 + j] + BN_EPS);
  t0[rloc][j] = lrelu_f((z[row*64 + j] - mean)*inv*gg[j] + be[j]);
  __syncthreads();
  float a = l1b[j];
  for (int k = 0; k < 64; ++k) a = fmaf(t0[rloc][k], W1s[k*64 + j], a);
  t1[rloc][j] = lrelu_f(a);
  __syncthreads();
  if (j < 32) {
    float v = l2b[j];
    for (int k = 0; k < 64; ++k) v = fmaf(t1[rloc][k], W2s[k*32 + j], v);
    t2[rloc][j] = lrelu_f(v) + nf[row*32 + j];
  }
  __syncthreads();
  float av = epb1[j], bv = 0.f;
  for (int k = 0; k < 32; ++k) {
    float x = t2[rloc][k];
    av = fmaf(x, Was[k*64 + j], av);
    bv = fmaf(x, Wbs[k*64 + j], bv);
  }
  A[row*64 + j] = av;
  Bm[row*64 + j] = bv;
}

// ---------------------------------------------------------------------------
// pack ep_w2/ep_w3 into bf16 B-fragments with k = 8g+b bijection (consistent
// with the A-fragment packing in k_edges_mfma — consistency is all MFMA needs)
__global__ void k_prepw(const float* __restrict__ W2, const float* __restrict__ W3,
                        unsigned short* __restrict__ out) {
  int i = blockIdx.x*256 + threadIdx.x;  // 8192 total
  if (i >= 8192) return;
  int mat = i >> 12, r = i & 4095;
  int k = r >> 6, c = r & 63;
  int q = k >> 5, g = (k >> 3) & 3, b = k & 7;
  int n = c >> 4, cc = c & 15;
  int lane = g*16 + cc;
  const float* W = mat ? W3 : W2;
  out[mat*4096 + ((q*4 + n)*64 + lane)*8 + b] = f2bf(W[r]);
}

__device__ __forceinline__ int ebase(int s) { return s*(2*NN - 1 - s)/2; }

// edge MLP via MFMA. Each wave: 16 edges/group, GPW groups.
__global__ __launch_bounds__(256) void k_edges_mfma(
    const float* __restrict__ A, const float* __restrict__ Bm,
    const unsigned short* __restrict__ Wf,
    const float* __restrict__ b2, const float* __restrict__ b3,
    const float* __restrict__ w4, const float* __restrict__ b4,
    float* __restrict__ out) {
  __shared__ __align__(16) unsigned short T[4][16*80];  // per-wave 16x64 tile, stride 80
  int tid = threadIdx.x;
  int wid = tid >> 6, lane = tid & 63;
  int c = lane & 15, g = lane >> 4;
  unsigned short* Tw = &T[wid][0];

  const v8bf* wp = (const v8bf*)Wf;
  v8bf w2f[8], w3f[8];
#pragma unroll
  for (int i = 0; i < 8; ++i) { w2f[i] = wp[i*64 + lane]; w3f[i] = wp[512 + i*64 + lane]; }
  float b2c[4], b3c[4], w4c[4];
#pragma unroll
  for (int n = 0; n < 4; ++n) { b2c[n] = b2[16*n + c]; b3c[n] = b3[16*n + c]; w4c[n] = w4[16*n + c]; }
  float b4v = b4[0];

  int wave_g = blockIdx.x*4 + wid;
  for (int it = 0; it < GPW; ++it) {
    int grp = wave_g*GPW + it;
    if (grp >= NGRP) break;           // uniform per wave
    int e = grp*16 + c;

    // decode (s,t) from triu linear index
    float disc = (float)((2*NN-1)*(2*NN-1) - 8*e);
    int s = (int)((2.f*NN - 1.f - sqrtf(disc)) * 0.5f);
    if (s < 0) s = 0;
    if (s > NN-2) s = NN-2;
    while (s > 0 && e < ebase(s)) --s;
    while (e >= ebase(s+1)) ++s;
    int t = s + 1 + (e - ebase(s));

    // build L1 = relu(A[s]+B[t]) directly as A-fragments (k = 32q + 8g + b)
    v8bf af[2];
#pragma unroll
    for (int q = 0; q < 2; ++q) {
      const float* ap = A  + s*64 + q*32 + g*8;
      const float* bp = Bm + t*64 + q*32 + g*8;
      f32x4 a0 = *(const f32x4*)ap,     a1 = *(const f32x4*)(ap + 4);
      f32x4 c0 = *(const f32x4*)bp,     c1 = *(const f32x4*)(bp + 4);
      union { v8bf v; unsigned short u[8]; } uu;
#pragma unroll
      for (int b = 0; b < 4; ++b) {
        uu.u[b]     = f2bf(fmaxf(a0[b] + c0[b], 0.f));
        uu.u[b + 4] = f2bf(fmaxf(a1[b] + c1[b], 0.f));
      }
      af[q] = uu.v;
    }

    // layer 2
    f32x4 acc[4];
#pragma unroll
    for (int n = 0; n < 4; ++n) { f32x4 z; z[0]=b2c[n]; z[1]=b2c[n]; z[2]=b2c[n]; z[3]=b2c[n]; acc[n]=z; }
#pragma unroll
    for (int n = 0; n < 4; ++n) acc[n] = __builtin_amdgcn_mfma_f32_16x16x32_bf16(af[0], w2f[n],     acc[n], 0, 0, 0);
#pragma unroll
    for (int n = 0; n < 4; ++n) acc[n] = __builtin_amdgcn_mfma_f32_16x16x32_bf16(af[1], w2f[4 + n], acc[n], 0, 0, 0);

    // relu -> bf16 -> LDS (D layout: row=(g*4+r), col=16n+c)
#pragma unroll
    for (int n = 0; n < 4; ++n)
#pragma unroll
      for (int r = 0; r < 4; ++r)
        Tw[(g*4 + r)*80 + n*16 + c] = f2bf(fmaxf(acc[n][r], 0.f));

    asm volatile("s_waitcnt lgkmcnt(0)" ::: "memory");

    // layer 3: A-fragments from T (same k = 32q+8g+b bijection as W3 pack)
    v8bf t0 = *(const v8bf*)(Tw + c*80 + g*8);
    v8bf t1 = *(const v8bf*)(Tw + c*80 + 32 + g*8);
#pragma unroll
    for (int n = 0; n < 4; ++n) { f32x4 z; z[0]=b3c[n]; z[1]=b3c[n]; z[2]=b3c[n]; z[3]=b3c[n]; acc[n]=z; }
#pragma unroll
    for (int n = 0; n < 4; ++n) acc[n] = __builtin_amdgcn_mfma_f32_16x16x32_bf16(t0, w3f[n],     acc[n], 0, 0, 0);
#pragma unroll
    for (int n = 0; n < 4; ++n) acc[n] = __builtin_amdgcn_mfma_f32_16x16x32_bf16(t1, w3f[4 + n], acc[n], 0, 0, 0);

    // layer 4: per-lane partials over the 4 col-tiles, reduce across 16-lane group
    float p0 = 0.f, p1 = 0.f, p2 = 0.f, p3 = 0.f;
#pragma unroll
    for (int n = 0; n < 4; ++n) {
      p0 = fmaf(fmaxf(acc[n][0], 0.f), w4c[n], p0);
      p1 = fmaf(fmaxf(acc[n][1], 0.f), w4c[n], p1);
      p2 = fmaf(fmaxf(acc[n][2], 0.f), w4c[n], p2);
      p3 = fmaf(fmaxf(acc[n][3], 0.f), w4c[n], p3);
    }
#pragma unroll
    for (int off = 1; off < 16; off <<= 1) {
      p0 += __shfl_xor(p0, off, 64);
      p1 += __shfl_xor(p1, off, 64);
      p2 += __shfl_xor(p2, off, 64);
      p3 += __shfl_xor(p3, off, 64);
    }
    // storing lanes: c<4 store edge m = g*4 + c (logit = p_{r=c})
    int m = (g*4 + c) & 15;
    int src = (lane & 48) | m;
    int sm = __shfl(s, src, 64);
    int tm = __shfl(t, src, 64);
    float sel = (c == 0) ? p0 : ((c == 1) ? p1 : ((c == 2) ? p2 : p3));
    float prob = 1.f / (1.f + expf(-(sel + b4v)));
    if (c < 4) {
      out[sm*NN + tm] = prob;
      out[tm*NN + sm] = prob;
    }
  }
}

__global__ void k_diag(float* __restrict__ out) {
  int i = blockIdx.x*256 + threadIdx.x;
  if (i < NN) out[i*NN + i] = 0.f;
}

// ---------------------------------------------------------------------------
extern "C" void kernel_launch(void* const* d_in, const int* in_sizes, int n_in,
                              void* d_out, int out_size, void* d_ws, size_t ws_size,
                              hipStream_t stream) {
  const float* nf     = (const float*)d_in[1];
  const float* c1_eps = (const float*)d_in[2];
  const float* c1_w1  = (const float*)d_in[3];
  const float* c1_b1  = (const float*)d_in[4];
  const float* c1_w2  = (const float*)d_in[5];
  const float* c1_b2  = (const float*)d_in[6];
  const float* c1_g   = (const float*)d_in[7];
  const float* c1_be  = (const float*)d_in[8];
  const float* cv_eps = (const float*)d_in[9];
  const float* cv_w1  = (const float*)d_in[10];
  const float* cv_b1  = (const float*)d_in[11];
  const float* cv_w2  = (const float*)d_in[12];
  const float* cv_b2  = (const float*)d_in[13];
  const float* cv_g   = (const float*)d_in[14];
  const float* cv_be  = (const float*)d_in[15];
  const float* lin1_w = (const float*)d_in[16];
  const float* lin1_b = (const float*)d_in[17];
  const float* lin2_w = (const float*)d_in[18];
  const float* lin2_b = (const float*)d_in[19];
  const float* ep_w1  = (const float*)d_in[20];
  const float* ep_b1  = (const float*)d_in[21];
  const float* ep_w2  = (const float*)d_in[22];
  const float* ep_b2  = (const float*)d_in[23];
  const float* ep_w3  = (const float*)d_in[24];
  const float* ep_b3  = (const float*)d_in[25];
  const float* ep_w4  = (const float*)d_in[26];
  const float* ep_b4  = (const float*)d_in[27];

  float* ws = (float*)d_ws;
  float* u     = ws;                 // [NN,64]
  float* z2    = u    + NN*64;       // [NN,64]
  float* Abuf  = z2   + NN*64;       // [NN,64]
  float* Bbuf  = Abuf + NN*64;       // [NN,64]
  float* stats = Bbuf + NN*64;       // [128]
  unsigned short* Wf = (unsigned short*)(stats + 128);  // [2][4096] bf16 frags

  dim3 b2d(64, 16);
  float* out = (float*)d_out;

  // weight fragment prep (independent; sequential on stream is fine)
  k_prepw<<<32, 256, 0, stream>>>(ep_w2, ep_w3, Wf);

  // GIN layer 1 (F=32 -> H=64)
  k_scan<<<1, b2d, 0, stream>>>(nf, FF, u, c1_eps, FF);
  k_mm2<<<NN/4, 256, 0, stream>>>(u, FF, c1_w1, c1_b1, c1_w2, c1_b2, z2);
  k_bnstats<<<1, b2d, 0, stream>>>(z2, stats);

  // GIN layer 2
  k_scanbn<<<1, b2d, 0, stream>>>(z2, stats, c1_g, c1_be, cv_eps + 0, u);
  k_mm2<<<NN/4, 256, 0, stream>>>(u, HH, cv_w1, cv_b1, cv_w2, cv_b2, z2);
  k_bnstats<<<1, b2d, 0, stream>>>(z2, stats);

  // GIN layer 3
  k_scanbn<<<1, b2d, 0, stream>>>(z2, stats, cv_g, cv_be, cv_eps + 1, u);
  k_mm2<<<NN/4, 256, 0, stream>>>(u, HH, cv_w1 + HH*HH, cv_b1 + HH, cv_w2 + HH*HH, cv_b2 + HH, z2);
  k_bnstats<<<1, b2d, 0, stream>>>(z2, stats);

  // head + edge-layer-1 factorization
  k_head<<<NN/4, 256, 0, stream>>>(z2, stats, cv_g + HH, cv_be + HH,
                                   lin1_w, lin1_b, lin2_w, lin2_b, nf,
                                   ep_w1, ep_b1, Abuf, Bbuf);

  // edge MLP (MFMA)
  k_edges_mfma<<<1024, 256, 0, stream>>>(Abuf, Bbuf, Wf, ep_b2, ep_b3, ep_w4, ep_b4, out);
  k_diag<<<(NN + 255)/256, 256, 0, stream>>>(out);
}

// Round 4
// 124.421 us; speedup vs baseline: 30.0525x; 1.4755x over previous
//
#include <hip/hip_runtime.h>
#include <math.h>

#define NN 1536
#define FF 32
#define HH 64
#define EE (NN*(NN-1)/2)   // 1178880 = 73680 * 16
#define NGRP (EE/16)       // 73680 groups of 16 edges
#define GPW 8              // groups per wave; 2304 blocks * 4 waves * 8 = 73728
#define EBLK 2304
#define BN_EPS 1e-5f
#define SLOPE 0.01f

typedef _Float16 v8h  __attribute__((ext_vector_type(8)));
typedef float    f32x4 __attribute__((ext_vector_type(4)));
typedef float    f32x8 __attribute__((ext_vector_type(8)));

union V8H { v8h v; float4 f4; };

__device__ __forceinline__ float lrelu_f(float v){ return v >= 0.f ? v : SLOPE*v; }

// ---------------------------------------------------------------------------
// layer-1 scan: u = (1+eps)*x + exclusive_prefix_sum(x). One block, 64x16.
__global__ void k_scan(const float* __restrict__ x, int ld,
                       float* __restrict__ u,
                       const float* __restrict__ eps_p, int D) {
  __shared__ float part[16][64];
  int c = threadIdx.x, w = threadIdx.y;
  const int chunk = NN / 16;  // 96
  float s = 0.f;
  if (c < D) for (int n = w*chunk; n < (w+1)*chunk; ++n) s += x[n*ld + c];
  part[w][c] = s;
  __syncthreads();
  if (c >= D) return;
  float run = 0.f;
  for (int i = 0; i < w; ++i) run += part[i][c];
  float e1 = 1.f + eps_p[0];
  for (int n = w*chunk; n < (w+1)*chunk; ++n) {
    float v = x[n*ld + c];
    u[n*64 + c] = e1*v + run;
    run += v;
  }
}

// BN-apply + lrelu + scan fused (layers 2..3 front-end)
__global__ void k_scanbn(const float* __restrict__ z, const float* __restrict__ stats,
                         const float* __restrict__ gg, const float* __restrict__ be,
                         const float* __restrict__ eps_p, float* __restrict__ u) {
  __shared__ float part[16][64];
  int c = threadIdx.x, w = threadIdx.y;
  float mean = stats[c], inv = rsqrtf(stats[64 + c] + BN_EPS);
  float ga = gg[c], bb = be[c];
  const int chunk = NN / 16;
  float s = 0.f;
  for (int n = w*chunk; n < (w+1)*chunk; ++n)
    s += lrelu_f((z[n*64 + c] - mean)*inv*ga + bb);
  part[w][c] = s;
  __syncthreads();
  float run = 0.f;
  for (int i = 0; i < w; ++i) run += part[i][c];
  float e1 = 1.f + eps_p[0];
  for (int n = w*chunk; n < (w+1)*chunk; ++n) {
    float hv = lrelu_f((z[n*64 + c] - mean)*inv*ga + bb);
    u[n*64 + c] = e1*hv + run;
    run += hv;
  }
}

// fused double matmul: z = relu(relu(u@W1+b1)@W2+b2). 4 rows/block.
__global__ __launch_bounds__(256) void k_mm2(
    const float* __restrict__ in, int Din,
    const float* __restrict__ W1, const float* __restrict__ b1,
    const float* __restrict__ W2, const float* __restrict__ b2,
    float* __restrict__ outz) {
  __shared__ float W1s[64*64];
  __shared__ float W2s[64*64];
  __shared__ float t1s[4][64];
  int tid = threadIdx.x;
  for (int i = tid; i < Din*64; i += 256) W1s[i] = W1[i];
  for (int i = tid; i < 4096; i += 256)   W2s[i] = W2[i];
  __syncthreads();
  int rloc = tid >> 6, j = tid & 63;
  int row = blockIdx.x*4 + rloc;
  const float* r = in + row*64;
  float a = b1[j];
  for (int k = 0; k < Din; ++k) a = fmaf(r[k], W1s[k*64 + j], a);
  t1s[rloc][j] = fmaxf(a, 0.f);
  __syncthreads();
  float z = b2[j];
  const float* tr = t1s[rloc];
  for (int k = 0; k < 64; ++k) z = fmaf(tr[k], W2s[k*64 + j], z);
  outz[row*64 + j] = fmaxf(z, 0.f);
}

// batch-norm statistics
__global__ void k_bnstats(const float* __restrict__ z, float* __restrict__ stats) {
  __shared__ float ps[16][64];
  __shared__ float pq[16][64];
  int c = threadIdx.x, w = threadIdx.y;
  const int chunk = NN / 16;
  float s = 0.f, q = 0.f;
  for (int n = w*chunk; n < (w+1)*chunk; ++n) {
    float v = z[n*64 + c];
    s += v; q += v*v;
  }
  ps[w][c] = s; pq[w][c] = q;
  __syncthreads();
  if (w == 0) {
    float S = 0.f, Q = 0.f;
    for (int i = 0; i < 16; ++i) { S += ps[i][c]; Q += pq[i][c]; }
    float mean = S / NN;
    stats[c] = mean;
    stats[64 + c] = Q / NN - mean*mean;
  }
}

// head: h3=lrelu(BN(z)); hf=lrelu(lrelu(h3@lin1)@lin2)+nf; A=hf@W1a+b1e; B=hf@W1b
// A,B written as f16 for the MFMA edge kernel.
__global__ __launch_bounds__(256) void k_head(
    const float* __restrict__ z, const float* __restrict__ stats,
    const float* __restrict__ gg, const float* __restrict__ be,
    const float* __restrict__ l1w, const float* __restrict__ l1b,
    const float* __restrict__ l2w, const float* __restrict__ l2b,
    const float* __restrict__ nf,
    const float* __restrict__ epw1, const float* __restrict__ epb1,
    _Float16* __restrict__ Ah, _Float16* __restrict__ Bh) {
  __shared__ float W1s[64*64];
  __shared__ float W2s[64*32];
  __shared__ float Was[32*64];
  __shared__ float Wbs[32*64];
  __shared__ float t0[4][64], t1[4][64], t2[4][32];
  int tid = threadIdx.x;
  for (int i = tid; i < 4096; i += 256) W1s[i] = l1w[i];
  for (int i = tid; i < 2048; i += 256) { W2s[i] = l2w[i]; Was[i] = epw1[i]; Wbs[i] = epw1[2048 + i]; }
  __syncthreads();
  int rloc = tid >> 6, j = tid & 63;
  int row = blockIdx.x*4 + rloc;
  float mean = stats[j], inv = rsqrtf(stats[64 + j] + BN_EPS);
  t0[rloc][j] = lrelu_f((z[row*64 + j] - mean)*inv*gg[j] + be[j]);
  __syncthreads();
  float a = l1b[j];
  for (int k = 0; k < 64; ++k) a = fmaf(t0[rloc][k], W1s[k*64 + j], a);
  t1[rloc][j] = lrelu_f(a);
  __syncthreads();
  if (j < 32) {
    float v = l2b[j];
    for (int k = 0; k < 64; ++k) v = fmaf(t1[rloc][k], W2s[k*32 + j], v);
    t2[rloc][j] = lrelu_f(v) + nf[row*32 + j];
  }
  __syncthreads();
  float av = epb1[j], bv = 0.f;
  for (int k = 0; k < 32; ++k) {
    float x = t2[rloc][k];
    av = fmaf(x, Was[k*64 + j], av);
    bv = fmaf(x, Wbs[k*64 + j], bv);
  }
  Ah[row*64 + j] = (_Float16)av;
  Bh[row*64 + j] = (_Float16)bv;
}

// ---------------------------------------------------------------------------
// Pack W2^T / W3^T as f16 MFMA A-fragments (swapped-operand edge MLP).
// Layer-2 k-bijection:  k(g,q,b) = 32q + 8g + b               (natural)
// Layer-3 k-bijection:  k(g,q,b) = 16*(2q+(b>>2)) + 4g + (b&3) (matches D-layout
//   of layer 2 so its output feeds layer 3's B-operand with NO transpose)
__global__ void k_prepw(const float* __restrict__ W2, const float* __restrict__ W3,
                        _Float16* __restrict__ out) {
  int i = blockIdx.x*256 + threadIdx.x;  // 8192 total
  if (i >= 8192) return;
  int mat = i >> 12, r = i & 4095;
  int k = r >> 6, cout = r & 63;         // k = input feature, cout = output feature
  int m = cout >> 4, c = cout & 15;
  int q, g, b;
  if (mat == 0) { q = k >> 5; g = (k >> 3) & 3; b = k & 7; }
  else { int mF = k >> 4; g = (k >> 2) & 3; int rr = k & 3; q = mF >> 1; b = ((mF & 1) << 2) | rr; }
  const float* W = mat ? W3 : W2;
  out[mat*4096 + ((q*4 + m)*64 + (g*16 + c))*8 + b] = (_Float16)W[r];
}

__device__ __forceinline__ int ebase(int s) { return s*(2*NN - 1 - s)/2; }

// edge MLP, swapped-operand MFMA: D = W^T (A) x activations^T (B).
// Lane (c,g): edge = c (preserved across BOTH layers), features 16m+4g+r in D.
// Zero LDS, zero lane transposes. f16 inputs, f32 accumulate.
__global__ __launch_bounds__(256) void k_edges_f16(
    const _Float16* __restrict__ Ah, const _Float16* __restrict__ Bh,
    const _Float16* __restrict__ Wf,
    const float* __restrict__ b2, const float* __restrict__ b3,
    const float* __restrict__ w4, const float* __restrict__ b4,
    float* __restrict__ out) {
  int tid = threadIdx.x, wid = tid >> 6, lane = tid & 63;
  int c = lane & 15, g = lane >> 4;

  const v8h* wp = (const v8h*)Wf;
  v8h wv2[8], wv3[8];
#pragma unroll
  for (int f = 0; f < 8; ++f) { wv2[f] = wp[f*64 + lane]; wv3[f] = wp[512 + f*64 + lane]; }

  float b2c[16], b3c[16], w4c[16];
  int g4 = g*4;
#pragma unroll
  for (int i = 0; i < 16; ++i) {
    int f = (i >> 2)*16 + g4 + (i & 3);
    b2c[i] = b2[f]; b3c[i] = b3[f]; w4c[i] = w4[f];
  }
  float b4v = b4[0];

  V8H zu; zu.f4 = make_float4(0.f, 0.f, 0.f, 0.f);
  const v8h vzero = zu.v;

  int grp = (blockIdx.x*4 + wid)*GPW;
  if (grp >= NGRP) return;

  // initial decode of edge e = grp*16 + c -> (s,t)
  int e = grp*16 + c;
  float disc = (float)((2*NN-1)*(2*NN-1) - 8*e);
  int s = (int)((2.f*NN - 1.f - sqrtf(disc)) * 0.5f);
  if (s < 0) s = 0;
  if (s > NN-2) s = NN-2;
  while (s > 0 && e < ebase(s)) --s;
  while (e >= ebase(s+1)) ++s;
  int t = s + 1 + (e - ebase(s));

  for (int it = 0; it < GPW; ++it, ++grp) {
    if (grp >= NGRP) break;

    // ---- L1 = relu(A[s]+B[t]) as two B-fragments (k = 32q+8g+b) ----
    V8H x0, x1, y0, y1, f0, f1;
    x0.f4 = *(const float4*)(Ah + s*64 + g*8);
    x1.f4 = *(const float4*)(Ah + s*64 + 32 + g*8);
    y0.f4 = *(const float4*)(Bh + t*64 + g*8);
    y1.f4 = *(const float4*)(Bh + t*64 + 32 + g*8);
    f0.v = __builtin_elementwise_max(x0.v + y0.v, vzero);   // v_pk_add/max_f16
    f1.v = __builtin_elementwise_max(x1.v + y1.v, vzero);

    // ---- layer 2: acc[m][r] = feature 16m+4g+r of edge c ----
    f32x4 acc[4];
#pragma unroll
    for (int m = 0; m < 4; ++m) {
      f32x4 z; z[0]=b2c[4*m]; z[1]=b2c[4*m+1]; z[2]=b2c[4*m+2]; z[3]=b2c[4*m+3];
      acc[m] = z;
    }
#pragma unroll
    for (int m = 0; m < 4; ++m)
      acc[m] = __builtin_amdgcn_mfma_f32_16x16x32_f16(wv2[m],     f0.v, acc[m], 0, 0, 0);
#pragma unroll
    for (int m = 0; m < 4; ++m)
      acc[m] = __builtin_amdgcn_mfma_f32_16x16x32_f16(wv2[4 + m], f1.v, acc[m], 0, 0, 0);

    // ---- relu (f32) + pack to f16: D-layout feeds layer-3 B-frags directly ----
    f32x8 q0, q1;
#pragma unroll
    for (int r = 0; r < 4; ++r) {
      q0[r]     = fmaxf(acc[0][r], 0.f);
      q0[4 + r] = fmaxf(acc[1][r], 0.f);
      q1[r]     = fmaxf(acc[2][r], 0.f);
      q1[4 + r] = fmaxf(acc[3][r], 0.f);
    }
    v8h p0 = __builtin_convertvector(q0, v8h);
    v8h p1 = __builtin_convertvector(q1, v8h);

    // ---- layer 3 ----
    f32x4 acc3[4];
#pragma unroll
    for (int m = 0; m < 4; ++m) {
      f32x4 z; z[0]=b3c[4*m]; z[1]=b3c[4*m+1]; z[2]=b3c[4*m+2]; z[3]=b3c[4*m+3];
      acc3[m] = z;
    }
#pragma unroll
    for (int m = 0; m < 4; ++m)
      acc3[m] = __builtin_amdgcn_mfma_f32_16x16x32_f16(wv3[m],     p0, acc3[m], 0, 0, 0);
#pragma unroll
    for (int m = 0; m < 4; ++m)
      acc3[m] = __builtin_amdgcn_mfma_f32_16x16x32_f16(wv3[4 + m], p1, acc3[m], 0, 0, 0);

    // ---- layer 4: per-lane partial over this lane's 16 features, reduce over g ----
    float p = 0.f;
#pragma unroll
    for (int m = 0; m < 4; ++m)
#pragma unroll
      for (int r = 0; r < 4; ++r)
        p = fmaf(fmaxf(acc3[m][r], 0.f), w4c[4*m + r], p);
    p += __shfl_xor(p, 16, 64);
    p += __shfl_xor(p, 32, 64);
    float prob = 1.f / (1.f + expf(-(p + b4v)));
    if (lane < 16) out[s*NN + t] = prob;   // upper triangle only, coalesced

    // ---- incremental edge advance ----
    t += 16;
    while (t >= NN && s < NN-1) { int o = t - NN; ++s; t = s + 1 + o; }
  }
}

// mirror: lower = upper^T, diag = 0. LDS-tiled, coalesced both ways.
__global__ __launch_bounds__(256) void k_mirror(float* __restrict__ out) {
  __shared__ float tile[32][33];
  int bi = blockIdx.y, bj = blockIdx.x;
  if (bi < bj) return;                       // strictly-upper tile: already written
  int i0 = bi*32, j0 = bj*32;
  int tx = threadIdx.x, ty = threadIdx.y;    // block (32,8)
#pragma unroll
  for (int r = 0; r < 4; ++r)
    tile[ty + r*8][tx] = out[(j0 + ty + r*8)*NN + i0 + tx];
  __syncthreads();
#pragma unroll
  for (int r = 0; r < 4; ++r) {
    int row = ty + r*8;
    int i = i0 + row, j = j0 + tx;
    if (bi > bj)      out[i*NN + j] = tile[tx][row];
    else if (i > j)   out[i*NN + j] = tile[tx][row];
    else if (i == j)  out[i*NN + j] = 0.f;
  }
}

// ---------------------------------------------------------------------------
extern "C" void kernel_launch(void* const* d_in, const int* in_sizes, int n_in,
                              void* d_out, int out_size, void* d_ws, size_t ws_size,
                              hipStream_t stream) {
  const float* nf     = (const float*)d_in[1];
  const float* c1_eps = (const float*)d_in[2];
  const float* c1_w1  = (const float*)d_in[3];
  const float* c1_b1  = (const float*)d_in[4];
  const float* c1_w2  = (const float*)d_in[5];
  const float* c1_b2  = (const float*)d_in[6];
  const float* c1_g   = (const float*)d_in[7];
  const float* c1_be  = (const float*)d_in[8];
  const float* cv_eps = (const float*)d_in[9];
  const float* cv_w1  = (const float*)d_in[10];
  const float* cv_b1  = (const float*)d_in[11];
  const float* cv_w2  = (const float*)d_in[12];
  const float* cv_b2  = (const float*)d_in[13];
  const float* cv_g   = (const float*)d_in[14];
  const float* cv_be  = (const float*)d_in[15];
  const float* lin1_w = (const float*)d_in[16];
  const float* lin1_b = (const float*)d_in[17];
  const float* lin2_w = (const float*)d_in[18];
  const float* lin2_b = (const float*)d_in[19];
  const float* ep_w1  = (const float*)d_in[20];
  const float* ep_b1  = (const float*)d_in[21];
  const float* ep_w2  = (const float*)d_in[22];
  const float* ep_b2  = (const float*)d_in[23];
  const float* ep_w3  = (const float*)d_in[24];
  const float* ep_b3  = (const float*)d_in[25];
  const float* ep_w4  = (const float*)d_in[26];
  const float* ep_b4  = (const float*)d_in[27];

  float* ws = (float*)d_ws;
  float* u     = ws;                 // [NN,64] f32
  float* z2    = u  + NN*64;         // [NN,64] f32
  float* stats = z2 + NN*64;         // [128]  f32
  _Float16* Ah = (_Float16*)(stats + 128);  // [NN,64] f16
  _Float16* Bh = Ah + NN*64;                // [NN,64] f16
  _Float16* Wf = Bh + NN*64;                // [2][4096] f16 fragments

  dim3 b2d(64, 16);
  float* out = (float*)d_out;

  // weight fragment prep (independent)
  k_prepw<<<32, 256, 0, stream>>>(ep_w2, ep_w3, Wf);

  // GIN layer 1 (F=32 -> H=64)
  k_scan<<<1, b2d, 0, stream>>>(nf, FF, u, c1_eps, FF);
  k_mm2<<<NN/4, 256, 0, stream>>>(u, FF, c1_w1, c1_b1, c1_w2, c1_b2, z2);
  k_bnstats<<<1, b2d, 0, stream>>>(z2, stats);

  // GIN layer 2
  k_scanbn<<<1, b2d, 0, stream>>>(z2, stats, c1_g, c1_be, cv_eps + 0, u);
  k_mm2<<<NN/4, 256, 0, stream>>>(u, HH, cv_w1, cv_b1, cv_w2, cv_b2, z2);
  k_bnstats<<<1, b2d, 0, stream>>>(z2, stats);

  // GIN layer 3
  k_scanbn<<<1, b2d, 0, stream>>>(z2, stats, cv_g, cv_be, cv_eps + 1, u);
  k_mm2<<<NN/4, 256, 0, stream>>>(u, HH, cv_w1 + HH*HH, cv_b1 + HH, cv_w2 + HH*HH, cv_b2 + HH, z2);
  k_bnstats<<<1, b2d, 0, stream>>>(z2, stats);

  // head + edge-layer-1 factorization (f16 outputs)
  k_head<<<NN/4, 256, 0, stream>>>(z2, stats, cv_g + HH, cv_be + HH,
                                   lin1_w, lin1_b, lin2_w, lin2_b, nf,
                                   ep_w1, ep_b1, Ah, Bh);

  // edge MLP (swapped-operand MFMA, zero LDS)
  k_edges_f16<<<EBLK, 256, 0, stream>>>(Ah, Bh, Wf, ep_b2, ep_b3, ep_w4, ep_b4, out);

  // mirror lower triangle + zero diagonal
  k_mirror<<<dim3(48, 48), dim3(32, 8), 0, stream>>>(out);
}